// Round 6
// baseline (99.690 us; speedup 1.0000x reference)
//
#include <hip/hip_runtime.h>
#include <math.h>

#define SEQ   64
#define DIM   512
#define NOSC  14
#define NSTEP 100
#define RPB   4     // rows per block

typedef float f4 __attribute__((ext_vector_type(4)));

// DPP sums (bound_ctrl=1). Patterns are local to each 16-lane row, so four
// independent 16-lane reductions coexist in one 64-lane wave.
__device__ __forceinline__ float dpp_sum4(float v) {   // sum within quad
    v += __int_as_float(__builtin_amdgcn_update_dpp(0, __float_as_int(v), 0xB1,  0xF, 0xF, true));
    v += __int_as_float(__builtin_amdgcn_update_dpp(0, __float_as_int(v), 0x4E,  0xF, 0xF, true));
    return v;
}
__device__ __forceinline__ float dpp_sum16(float v) {  // sum within 16-lane row
    v += __int_as_float(__builtin_amdgcn_update_dpp(0, __float_as_int(v), 0xB1,  0xF, 0xF, true));
    v += __int_as_float(__builtin_amdgcn_update_dpp(0, __float_as_int(v), 0x4E,  0xF, 0xF, true));
    v += __int_as_float(__builtin_amdgcn_update_dpp(0, __float_as_int(v), 0x141, 0xF, 0xF, true));
    v += __int_as_float(__builtin_amdgcn_update_dpp(0, __float_as_int(v), 0x140, 0xF, 0xF, true));
    return v;
}

// HW trig: v_sin_f32 / v_cos_f32 take REVOLUTIONS; reduce with fract first.
__device__ __forceinline__ void fast_sincos(float theta, float* s, float* c) {
    const float inv2pi = 0.15915494309189535f;
    float r = theta * inv2pi;
    r = r - floorf(r);
    *s = __builtin_amdgcn_sinf(r);
    *c = __builtin_amdgcn_cosf(r);
}

// Barrier-free intra-block producer/consumer pipeline. Each block owns RPB rows.
//   wave 0: rows 0,2  — load+pool+project+flag (self-contained, no barriers)
//   wave 1: rows 1,3  — same
//   wave 2: exits
//   wave 3: consumer — 4x16-lane groups scan the 4 rows in ONE pass at the end
// Sync: LDS flags, release/acquire, workgroup scope. One __syncthreads at start
// (flag init) only.
__global__ __launch_bounds__(256, 4)
void fused_kernel(const float* __restrict__ x,
                  const float* __restrict__ W_in,
                  const float* __restrict__ b_in,
                  const float* __restrict__ omega,
                  const float* __restrict__ Wc,
                  const float* __restrict__ bc,
                  float* __restrict__ out, int B)
{
    const int t    = threadIdx.x;
    const int wv   = t >> 6;
    const int ln   = t & 63;
    const int row0 = blockIdx.x * RPB;

    __shared__ f4    mvbuf[2][2][DIM / 4];   // [producer wave][row parity][chunk]
    __shared__ float th0[RPB][16];           // theta0 per row
    __shared__ int   flags[RPB];

    if (t < RPB) flags[t] = 0;
    __syncthreads();                          // the only block-wide barrier

    if (wv < 2) {
        // ---------------- producer wave: rows wv, wv+2 ----------------
        const int o = ln >> 2;                // oscillator (0..15), 4 lanes each
        const int q = ln & 3;                 // quarter of the 512-dim dot
        for (int rr = 0; rr < RPB / 2; ++rr) {
            const int r   = wv + 2 * rr;
            const int row = row0 + r;
            if (row >= B) break;

            const f4* xv = reinterpret_cast<const f4*>(x + (size_t)row * (SEQ * DIM));
            f4 a0 = (f4)(0.0f), a1 = (f4)(0.0f);
#pragma unroll 8
            for (int s = 0; s < SEQ; ++s) {
                a0 += __builtin_nontemporal_load(&xv[s * (DIM / 4) + ln]);
                a1 += __builtin_nontemporal_load(&xv[s * (DIM / 4) + 64 + ln]);
            }
            f4* mw = mvbuf[wv][rr & 1];
            mw[ln]      = a0 * (1.0f / SEQ);
            mw[ln + 64] = a1 * (1.0f / SEQ);
            asm volatile("s_waitcnt lgkmcnt(0)" ::: "memory");  // wave-local LDS visibility

            // projection: lane (o,q) covers d = q*128 .. q*128+127 for oscillator o
            const float* m = reinterpret_cast<const float*>(mw);
            float p = 0.f;
            if (o < NOSC) {
#pragma unroll 16
                for (int i = 0; i < 128; ++i) {
                    const int d = q * 128 + i;
                    p += m[d] * W_in[d * NOSC + o];
                }
            }
            p = dpp_sum4(p);                  // full dot in every quad lane
            if (q == 0) th0[r][o] = (o < NOSC) ? (p + b_in[o]) : 0.f;
            if (ln == 0)
                __hip_atomic_store(&flags[r], 1, __ATOMIC_RELEASE, __HIP_MEMORY_SCOPE_WORKGROUP);
        }
    } else if (wv == 3) {
        // ---------------- consumer wave: 4 rows in one pass ----------------
        const int grp = ln >> 4;              // 0..3 -> row row0+grp
        const int o   = ln & 15;
        const int row = row0 + grp;
        if (row < B) {
            while (__hip_atomic_load(&flags[grp], __ATOMIC_ACQUIRE, __HIP_MEMORY_SCOPE_WORKGROUP) == 0)
                __builtin_amdgcn_s_sleep(4);

            const bool  act  = (o < NOSC);
            const float mask = act ? 1.0f : 0.0f;
            const int   oc   = act ? o : (NOSC - 1);

            float theta = th0[grp][o];        // 0 for padded slots
            const float drift = 6.283185307179586f * omega[oc];
            const float kn = 1.5f / (float)NOSC;
            const float dt = 0.01f;

            for (int it = 0; it < NSTEP; ++it) {
                float s_, c_;
                fast_sincos(theta, &s_, &c_);
                s_ *= mask; c_ *= mask;
                const float S = dpp_sum16(s_);
                const float C = dpp_sum16(c_);
                theta += dt * (drift + kn * (S * c_ - C * s_));
            }

            float hs, hc;
            fast_sincos(theta, &hs, &hc);
            const float h = hc * mask;
            float z0 = dpp_sum16(h * Wc[oc * 2 + 0]);
            float z1 = dpp_sum16(h * Wc[oc * 2 + 1]);
            if (o == 0) {
                z0 += bc[0]; z1 += bc[1];
                const float mx  = fmaxf(z0, z1);
                const float lse = mx + logf(expf(z0 - mx) + expf(z1 - mx));
                out[(size_t)row * 2 + 0] = z0 - lse;
                out[(size_t)row * 2 + 1] = z1 - lse;
            }
        }
    }
    // wave 2 falls through and exits immediately
}

extern "C" void kernel_launch(void* const* d_in, const int* in_sizes, int n_in,
                              void* d_out, int out_size, void* d_ws, size_t ws_size,
                              hipStream_t stream)
{
    const float* x     = (const float*)d_in[0];
    const float* W_in  = (const float*)d_in[1];
    const float* b_in  = (const float*)d_in[2];
    const float* omega = (const float*)d_in[3];
    const float* Wc    = (const float*)d_in[4];
    const float* bc    = (const float*)d_in[5];
    float* out = (float*)d_out;

    const int B = in_sizes[0] / (SEQ * DIM);   // 4096

    const int grid = (B + RPB - 1) / RPB;      // 1024 = 4 blocks/CU x 256 CU
    fused_kernel<<<grid, 256, 0, stream>>>(x, W_in, b_in, omega, Wc, bc, out, B);
}